// Round 6
// baseline (367.133 us; speedup 1.0000x reference)
//
#include <hip/hip_runtime.h>

// DendralNeuron: out[b,d] = min( min_f(x[b,f]-Wmin[d,f]), min_f(Wmax[d,f]-x[b,f]) )
// Tropical "min-GEMM". R9 changes vs R8 (47.4us, VALU-issue 30.7us = 2.9x the
// 10.5us math floor -> address-machinery bloat):
//  (a) kc-loop FULLY UNROLLED (CPZ=7 static): x loads become base+immediate
//      (j*32+f*16 <= 240B fits 13-bit signed offset), W prefetch likewise;
//      4 pointer setups per z-slice instead of per f-step; double-buffer
//      index j&1 static. Unrolled body lets the scheduler hoist global loads
//      across barriers (ILP latency hiding; occupancy is only 16 waves/CU).
//  (b) VGPR 65..128 all give the same 16-waves/CU cap (m69 quantization) ->
//      free headroom for the unroll. Keep __launch_bounds__(256,2): R4
//      proved (256,4) squeezes to 64 VGPR and spills.
//  (c) everything else from R8 kept: W-only LDS (x via L1 broadcast loads),
//      12.3KB LDS, grid 16x8x14 = 1792 blocks = 7/CU, merged accumulator
//      (2 VALU insts per (b,d,f) triple = ISA floor: v_pk_add_f32 + v_min3).

constexpr int F_DIM = 784;
constexpr int BM = 64;
constexpr int BN = 64;
constexpr int BK = 8;
constexpr int LSTR = BK + 4;          // 12 floats: rows 48B apart, 16B-aligned
constexpr int NCHUNK = F_DIM / BK;    // 98
constexpr int ZSPLIT = 14;            // F-split: 7 chunks of 8 per z-slice
constexpr int CPZ = NCHUNK / ZSPLIT;  // 7 (compile-time -> full unroll)

typedef float f4v __attribute__((ext_vector_type(4)));
typedef float f2v __attribute__((ext_vector_type(2)));

__global__ __launch_bounds__(256, 4)
void dendral_init_kernel(float* __restrict__ out) {
  const int i = blockIdx.x * 256 + threadIdx.x;
  const float inf = __builtin_inff();
  f4v v = {inf, inf, inf, inf};
  ((f4v*)out)[i] = v;
}

__device__ inline void atomic_min_float(float* addr, float v) {
  if (v >= 0.0f) atomicMin((int*)addr, __float_as_int(v));
  else           atomicMax((unsigned int*)addr, __float_as_uint(v));
}

__global__ __launch_bounds__(256, 2)
void dendral_min_kernel(const float* __restrict__ x,
                        const float* __restrict__ wmin,
                        const float* __restrict__ wmax,
                        float* __restrict__ out, int D) {
  __shared__ float lwn[2][BN * LSTR];   // wmin tile [64][12] x2 buf
  __shared__ float lwx[2][BN * LSTR];   // wmax tile [64][12] x2 buf

  const int t  = threadIdx.x;
  const int tx = t & 15;              // d-group: cols tx + 16c, c=0..3
  const int ty = t >> 4;              // b-group: rows ty + 16r, r=0..3
  const int b0 = blockIdx.x * BM;
  const int d0 = blockIdx.y * BN;
  const int c0 = blockIdx.z * CPZ;

  // W staging: wmin+wmax tiles 2 x 64x8 = 256 float4 (1/thread, wave split).
  const int wt = t >> 7;              // 0 -> wmin (waves 0,1), 1 -> wmax (2,3)
  const int wr = (t & 127) >> 1;      // 0..63
  const int wc = (t & 1) << 2;        // 0 or 4

  // Bases for this z-slice; all subsequent offsets are compile-time imms.
  const float* wgb = (wt ? wmax : wmin) + (size_t)(d0 + wr) * F_DIM
                     + c0 * BK + wc;
  float* lds_w = (wt ? &lwx[0][0] : &lwn[0][0]) + wr * LSTR + wc;
  constexpr int BUFSTRIDE_W = BN * LSTR;

  // x row base pointers (broadcast loads: 16 lanes share each address).
  const float* xb0 = x + (size_t)(b0 + ty)      * F_DIM + c0 * BK;
  const float* xb1 = x + (size_t)(b0 + ty + 16) * F_DIM + c0 * BK;
  const float* xb2 = x + (size_t)(b0 + ty + 32) * F_DIM + c0 * BK;
  const float* xb3 = x + (size_t)(b0 + ty + 48) * F_DIM + c0 * BK;

  // Stage chunk 0's W into buffer 0.
  *(f4v*)lds_w = *(const f4v*)wgb;
  __syncthreads();

  float acc[4][4];
#pragma unroll
  for (int r = 0; r < 4; ++r)
#pragma unroll
    for (int c = 0; c < 4; ++c)
      acc[r][c] = __builtin_inff();

#pragma unroll
  for (int j = 0; j < CPZ; ++j) {     // STATIC trip count -> full unroll
    f4v pw;
    if (j + 1 < CPZ)                  // next chunk's W: base + immediate
      pw = *(const f4v*)(wgb + (j + 1) * BK);

    const float* lnb = &lwn[j & 1][tx * LSTR];
    const float* lwb = &lwx[j & 1][tx * LSTR];
#pragma unroll
    for (int f = 0; f < BK; f += 4) {
      // x fragments: direct global, base + immediate offset (L1 broadcast).
      f4v xv[4];
      xv[0] = *(const f4v*)(xb0 + j * BK + f);
      xv[1] = *(const f4v*)(xb1 + j * BK + f);
      xv[2] = *(const f4v*)(xb2 + j * BK + f);
      xv[3] = *(const f4v*)(xb3 + j * BK + f);
      f4v nv[4], wv[4];
#pragma unroll
      for (int c = 0; c < 4; ++c) {
        nv[c] = *(const f4v*)&lnb[c * 16 * LSTR + f];
        wv[c] = *(const f4v*)&lwb[c * 16 * LSTR + f];
      }
#pragma unroll
      for (int r = 0; r < 4; ++r)
#pragma unroll
        for (int c = 0; c < 4; ++c) {
          // d1 = x - wmin (L1 path), d2 = wmax - x (L2 path); packed subs.
          f2v d1lo = xv[r].xy - nv[c].xy;
          f2v d1hi = xv[r].zw - nv[c].zw;
          f2v d2lo = wv[c].xy - xv[r].xy;
          f2v d2hi = wv[c].zw - xv[r].zw;
          // 8-value min + acc folded via 4 v_min3.
          float t1 = fminf(fminf(d1lo.x, d1lo.y), d1hi.x);
          float t2 = fminf(fminf(d1hi.y, d2lo.x), d2lo.y);
          float t3 = fminf(fminf(d2hi.x, d2hi.y), acc[r][c]);
          acc[r][c] = fminf(fminf(t1, t2), t3);
        }
    }

    if (j + 1 < CPZ) {                // stage next chunk's W (static buffer)
      *(f4v*)(lds_w + ((j + 1) & 1) * BUFSTRIDE_W) = pw;
    }
    __syncthreads();
  }

  // Combine this z-slice's partial into out via device-scope atomic min.
#pragma unroll
  for (int r = 0; r < 4; ++r)
#pragma unroll
    for (int c = 0; c < 4; ++c) {
      const int b = b0 + ty + 16 * r;
      const int d = d0 + tx + 16 * c;
      atomic_min_float(&out[(size_t)b * D + d], acc[r][c]);
    }
}

extern "C" void kernel_launch(void* const* d_in, const int* in_sizes, int n_in,
                              void* d_out, int out_size, void* d_ws, size_t ws_size,
                              hipStream_t stream) {
  const float* x    = (const float*)d_in[0];
  const float* wmin = (const float*)d_in[1];
  const float* wmax = (const float*)d_in[2];
  float* out = (float*)d_out;
  const int B = in_sizes[0] / F_DIM;    // 1024 (element-count convention)
  const int D = in_sizes[1] / F_DIM;    // 512

  // Full-coverage init: B*D floats / (4 per thread * 256 threads) blocks.
  dendral_init_kernel<<<(B * D) / 1024, 256, 0, stream>>>(out);

  dim3 grid(B / BM, D / BN, ZSPLIT);    // 16 x 8 x 14 = 1792 blocks = 7/CU
  dendral_min_kernel<<<grid, 256, 0, stream>>>(x, wmin, wmax, out, D);
  (void)n_in; (void)d_ws; (void)ws_size; (void)out_size;
}

// Round 7
// 98.969 us; speedup vs baseline: 3.7096x; 3.7096x over previous
//
#include <hip/hip_runtime.h>

// DendralNeuron: out[b,d] = min( min_f(x[b,f]-Wmin[d,f]), min_f(Wmax[d,f]-x[b,f]) )
// Tropical "min-GEMM". R10 vs R8 (47.4us; R9's full unroll spilled, reverted):
//  (a) BM=128 x BN=32 (r=8, c=2 per thread): W ds_reads per f-step 8 -> 4
//      serving the same 16 outputs -> LDS-pipe floor 15.7 -> 7.9us.
//  (b) whole 56-feature W slice staged ONCE (15.4KB LDS, LSTR=60 rows stay
//      16B-aligned, 2-way banks = free): ONE barrier per block (was 7),
//      no double buffer, no prefetch regs.
//  (c) all hot-loop addresses are invariant-base + fi*16 immediates (13-bit
//      global / 16-bit DS range) -> in-loop addressing VALU ~0.
//  (d) f-loop DYNAMIC with #pragma unroll 2 -- NOT fully unrolled: R9 proved
//      hoisting a slice's worth of global loads explodes live ranges and
//      spills (FETCH 560MB/WRITE 643MB scratch). Window stays <= 2 f-steps.
//  (e) keep __launch_bounds__(256,2): R4 proved (256,4) squeezes to 64 VGPR.
// Inner math unchanged: 4 v_pk_add_f32 + 4 v_min3 per (r,c)-per-4-features
// = 2 VALU insts per (b,d,f) triple = ISA floor (no packed f32 min exists).

constexpr int F_DIM = 784;
constexpr int BM = 128;
constexpr int BN = 32;
constexpr int ZSPLIT = 14;            // F-split: 56 features per z-slice
constexpr int FS = F_DIM / ZSPLIT;    // 56
constexpr int LSTR = 60;              // 240B rows: 16B-aligned, 2-way banks
constexpr int NF4 = FS / 4;           // 14 f4v per W row

typedef float f4v __attribute__((ext_vector_type(4)));
typedef float f2v __attribute__((ext_vector_type(2)));

__global__ __launch_bounds__(256, 4)
void dendral_init_kernel(float* __restrict__ out) {
  const int i = blockIdx.x * 256 + threadIdx.x;
  const float inf = __builtin_inff();
  f4v v = {inf, inf, inf, inf};
  ((f4v*)out)[i] = v;
}

__device__ inline void atomic_min_float(float* addr, float v) {
  if (v >= 0.0f) atomicMin((int*)addr, __float_as_int(v));
  else           atomicMax((unsigned int*)addr, __float_as_uint(v));
}

__global__ __launch_bounds__(256, 2)
void dendral_min_kernel(const float* __restrict__ x,
                        const float* __restrict__ wmin,
                        const float* __restrict__ wmax,
                        float* __restrict__ out, int D) {
  __shared__ float lwn[BN * LSTR];    // wmin slice [32][60 (56 used)]
  __shared__ float lwx[BN * LSTR];    // wmax slice [32][60 (56 used)]

  const int t  = threadIdx.x;
  const int tx = t & 15;              // d-group: cols tx, tx+16
  const int ty = t >> 4;              // b-group: rows ty + 16r, r=0..7
  const int b0 = blockIdx.x * BM;
  const int d0 = blockIdx.y * BN;
  const int f0 = blockIdx.z * FS;     // feature-slice start

  // ---- Stage whole W slice: 64 rows (32 wmin + 32 wmax) x 14 f4v = 896.
  // i = t + 256k, k=0..3 (last quarter half-filled). Consecutive i walk
  // columns within a row -> 224B coalesced runs per row.
#pragma unroll
  for (int k = 0; k < 4; ++k) {
    const int i = t + 256 * k;
    if (i < 64 * NF4) {
      const int row = i / NF4;        // 0..63
      const int c4  = i % NF4;        // 0..13
      const int wr  = row & 31;
      const float* src = (row < 32 ? wmin : wmax)
                         + (size_t)(d0 + wr) * F_DIM + f0 + c4 * 4;
      float* dst = (row < 32 ? lwn : lwx) + wr * LSTR + c4 * 4;
      *(f4v*)dst = *(const f4v*)src;
    }
  }
  __syncthreads();                    // the ONLY barrier

  // x row-base offset (VGPR, loop-invariant): row b0+ty, feature f0.
  const size_t xoff = (size_t)(b0 + ty) * F_DIM + f0;

  float acc[8][2];
#pragma unroll
  for (int r = 0; r < 8; ++r)
#pragma unroll
    for (int c = 0; c < 2; ++c)
      acc[r][c] = __builtin_inff();

  const float* lnb0 = &lwn[tx * LSTR];
  const float* lnb1 = &lwn[(tx + 16) * LSTR];
  const float* lwb0 = &lwx[tx * LSTR];
  const float* lwb1 = &lwx[(tx + 16) * LSTR];

#pragma unroll 2
  for (int fi = 0; fi < NF4; ++fi) {  // 14 f-steps of 4 features
    // x fragments: broadcast global loads (16 lanes share each address),
    // uniform base (r*16*F_DIM) + VGPR offset + fi*16B immediate.
    f4v xv[8];
#pragma unroll
    for (int r = 0; r < 8; ++r)
      xv[r] = *(const f4v*)(x + xoff + (size_t)r * 16 * F_DIM + fi * 4);
    // W fragments: 4 ds_read_b128, static addr + fi*16B immediate.
    f4v nv0 = *(const f4v*)(lnb0 + fi * 4);
    f4v nv1 = *(const f4v*)(lnb1 + fi * 4);
    f4v wv0 = *(const f4v*)(lwb0 + fi * 4);
    f4v wv1 = *(const f4v*)(lwb1 + fi * 4);
#pragma unroll
    for (int r = 0; r < 8; ++r) {
#pragma unroll
      for (int c = 0; c < 2; ++c) {
        const f4v nv = c ? nv1 : nv0;
        const f4v wv = c ? wv1 : wv0;
        // d1 = x - wmin (L1 path), d2 = wmax - x (L2 path); packed subs.
        f2v d1lo = xv[r].xy - nv.xy;
        f2v d1hi = xv[r].zw - nv.zw;
        f2v d2lo = wv.xy - xv[r].xy;
        f2v d2hi = wv.zw - xv[r].zw;
        // 8-value min + acc folded via 4 v_min3.
        float t1 = fminf(fminf(d1lo.x, d1lo.y), d1hi.x);
        float t2 = fminf(fminf(d1hi.y, d2lo.x), d2lo.y);
        float t3 = fminf(fminf(d2hi.x, d2hi.y), acc[r][c]);
        acc[r][c] = fminf(fminf(t1, t2), t3);
      }
    }
  }

  // Combine this z-slice's partial into out via device-scope atomic min.
#pragma unroll
  for (int r = 0; r < 8; ++r)
#pragma unroll
    for (int c = 0; c < 2; ++c) {
      const int b = b0 + ty + 16 * r;
      const int d = d0 + tx + 16 * c;
      atomic_min_float(&out[(size_t)b * D + d], acc[r][c]);
    }
}

extern "C" void kernel_launch(void* const* d_in, const int* in_sizes, int n_in,
                              void* d_out, int out_size, void* d_ws, size_t ws_size,
                              hipStream_t stream) {
  const float* x    = (const float*)d_in[0];
  const float* wmin = (const float*)d_in[1];
  const float* wmax = (const float*)d_in[2];
  float* out = (float*)d_out;
  const int B = in_sizes[0] / F_DIM;    // 1024 (element-count convention)
  const int D = in_sizes[1] / F_DIM;    // 512

  // Full-coverage init: B*D floats / (4 per thread * 256 threads) blocks.
  dendral_init_kernel<<<(B * D) / 1024, 256, 0, stream>>>(out);

  dim3 grid(B / BM, D / BN, ZSPLIT);    // 8 x 16 x 14 = 1792 blocks
  dendral_min_kernel<<<grid, 256, 0, stream>>>(x, wmin, wmax, out, D);
  (void)n_in; (void)d_ws; (void)ws_size; (void)out_size;
}